// Round 9
// baseline (146.509 us; speedup 1.0000x reference)
//
#include <hip/hip_runtime.h>

// qpNet: h = x @ W^T + b ; z = max(-h, -1000). x:[B,5] f32, W:[5,5], b:[5].
// B = 4194304. 168 MB app traffic (84r+84w). Mixed-stream floor ~27-31 us.
//
// R2:  80 B lane stride, one-shot      -> 57 us
// R3:  block LDS transpose + barrier   -> 50 us
// R5:  nt STORES @ 64B-stride layout   -> 82 us (partial-line nt = 1.76x WRITE)
// R6:  wave-private LDS transpose      -> ~50 us
// R7:  R6 + reg prefetch               -> 51.4 us (VGPR=28: prefetch sunk)
// R9:  no-LDS, 80 B stride             -> 61 us
// R10: R7 + sched_barrier pin          -> 49.6 us
// R11: global_load_lds dbuf vmcnt(10)  -> 50.2 us (overlap guaranteed; flat
//      BECAUSE the cache-allocation cap was binding, not concurrency)
// R12: shuffle kernel, no LDS          -> 53.4 us
// R13: R10 + NONTEMPORAL LOADS         -> kernel ~44 us, dur 151.4->145.8.
//      Cache-allocation traffic WAS the structure-invariant ~50 us cap.
// R14: + nt stores (full-line layout)  -> flat (146.2). Neutral; kept.
// R15 (this): re-test OVERLAP in the post-nt regime. R11's conclusion
//      ("depth doesn't matter") was measured under the cache cap and is
//      stale. Compose: R11 DMA double-buffer (10 VMEM structurally
//      outstanding/wave, counted vmcnt, zero VGPR liveness) + NT on the DMA
//      aux/CPol bits (NT=2 on gfx940+) + nt stores.
//      Fork (pre-committed): ~32-37 us kernel (dur ~134-139) => read
//      concurrency was the post-cache limiter. Flat (~145-147) => overlap
//      exonerated in both regimes; remaining gap = mixed-stream service
//      rate => ROOFLINE.

#define BLOCK 256
#define WAVES_PER_BLOCK 4          // BLOCK / 64
#define F4_PER_TILE 320            // 64 lanes * 5 f4 = 1280 floats = 256 rows
#define TILES_PER_WAVE 4           // 4096 waves total = 1024 blocks
#define TILE_FLOATS 1280
#define AUX_NT 2                   // CPol NT bit (gfx940+/gfx950)

typedef float vf4 __attribute__((ext_vector_type(4)));

typedef const __attribute__((address_space(1))) void gvoid_t;
typedef __attribute__((address_space(3))) void svoid_t;

__global__ __launch_bounds__(BLOCK) void qpnet_kernel(
    const float* __restrict__ x,
    const float* __restrict__ W,
    const float* __restrict__ bfc,
    float* __restrict__ out,
    int total_f4)
{
    // [wave][dbuf][1280 floats] = 40 KB
    __shared__ __align__(16) float lds[WAVES_PER_BLOCK * 2 * TILE_FLOATS];

    // 5x5 weights + bias (wave-uniform -> scalar-cached).
    float w[5][5];
    float bias[5];
#pragma unroll
    for (int j = 0; j < 5; ++j) {
        bias[j] = bfc[j];
#pragma unroll
        for (int i = 0; i < 5; ++i) w[j][i] = W[j * 5 + i];
    }

    const int wave = threadIdx.x >> 6;
    const int lane = threadIdx.x & 63;
    float* const wbuf = &lds[wave * (2 * TILE_FLOATS)];

    const int wave_id = blockIdx.x * WAVES_PER_BLOCK + wave;
    const int tb = wave_id * (F4_PER_TILE * TILES_PER_WAVE);  // f4 units
    if (tb >= total_f4) return;                               // exact division

    const vf4* __restrict__ xin  = reinterpret_cast<const vf4*>(x);
    vf4* __restrict__       zout = reinterpret_cast<vf4*>(out);

    // ---- prologue: NT-DMA tile 0 into buf0. Per instr k: lanes fill bytes
    // (k*64+lane)*16 of the buffer == the conflict-free stage-in layout.
#pragma unroll
    for (int k = 0; k < 5; ++k) {
        __builtin_amdgcn_global_load_lds(
            (gvoid_t*)(const void*)&xin[tb + k * 64 + lane],
            (svoid_t*)(void*)&wbuf[k * 256], 16, 0, AUX_NT);
    }

#pragma unroll
    for (int t = 0; t < TILES_PER_WAVE; ++t) {
        const int cur = tb + t * F4_PER_TILE;
        float* const cbuf = wbuf + (t & 1) * TILE_FLOATS;

        // ---- issue NEXT tile's NT-DMA into the other buffer (fire-and-forget,
        // no dest VGPRs -> nothing for the allocator to sink or spill).
        // WAR on that buffer is safe: tile t-2's stage-out ds_reads drained
        // at its lgkmcnt(0) before its global stores issued.
        if (t + 1 < TILES_PER_WAVE) {
            float* const nbuf = wbuf + ((t + 1) & 1) * TILE_FLOATS;
            const int nxt = cur + F4_PER_TILE;
#pragma unroll
            for (int k = 0; k < 5; ++k) {
                __builtin_amdgcn_global_load_lds(
                    (gvoid_t*)(const void*)&xin[nxt + k * 64 + lane],
                    (svoid_t*)(void*)&nbuf[k * 256], 16, 0, AUX_NT);
            }
        }

        // ---- counted wait: drain L(t) only; S(t-1)+L(t+1) stay in flight.
        // VMEM issue order per iter: L(t)[5], S(t-1)[5], L(t+1)[5]; in-order
        // retirement => vmcnt(10) guarantees L(t) landed in LDS.
        if (t == 0) {
            asm volatile("s_waitcnt vmcnt(5)" ::: "memory");   // only L1 younger
        } else if (t + 1 < TILES_PER_WAVE) {
            asm volatile("s_waitcnt vmcnt(10)" ::: "memory");  // S(t-1)+L(t+1)
        } else {
            asm volatile("s_waitcnt vmcnt(5)" ::: "memory");   // S(t-1) only
        }
        __builtin_amdgcn_sched_barrier(0);

        // ---- transposed read: own 20 consecutive floats = 4 complete rows
        // (word addr lane*20 + 4p: stride-20 f4 groups cover all 32 banks / 8 lanes)
        float v[20];
#pragma unroll
        for (int p = 0; p < 5; ++p)
            *reinterpret_cast<vf4*>(&v[4 * p]) =
                *reinterpret_cast<const vf4*>(&cbuf[lane * 20 + 4 * p]);

        // ---- compute: 4 rows x (5x5 matvec + bias + clamp), in place
#pragma unroll
        for (int k = 0; k < 4; ++k) {
            float t0 = bias[0], t1 = bias[1], t2 = bias[2], t3 = bias[3], t4 = bias[4];
#pragma unroll
            for (int i = 0; i < 5; ++i) {
                const float xv = v[k * 5 + i];
                t0 = fmaf(xv, w[0][i], t0);
                t1 = fmaf(xv, w[1][i], t1);
                t2 = fmaf(xv, w[2][i], t2);
                t3 = fmaf(xv, w[3][i], t3);
                t4 = fmaf(xv, w[4][i], t4);
            }
            v[k * 5 + 0] = fmaxf(-t0, -1000.0f);
            v[k * 5 + 1] = fmaxf(-t1, -1000.0f);
            v[k * 5 + 2] = fmaxf(-t2, -1000.0f);
            v[k * 5 + 3] = fmaxf(-t3, -1000.0f);
            v[k * 5 + 4] = fmaxf(-t4, -1000.0f);
        }

        // ---- transposed write back (in place, same buffer)
#pragma unroll
        for (int p = 0; p < 5; ++p)
            *reinterpret_cast<vf4*>(&cbuf[lane * 20 + 4 * p]) =
                *reinterpret_cast<const vf4*>(&v[4 * p]);
        // cross-lane exchange: drain DS writes before contiguous reads
        asm volatile("s_waitcnt lgkmcnt(0)" ::: "memory");

        // ---- stage out: LDS -> lane-contiguous NT global stores S(t).
        // Full-line coverage (16 complete 64B lines per wave instr): nt
        // streams whole lines, skips write-allocate (R14: neutral-or-better).
#pragma unroll
        for (int k = 0; k < 5; ++k) {
            const vf4 val = *reinterpret_cast<const vf4*>(&cbuf[(k * 64 + lane) * 4]);
            __builtin_nontemporal_store(val, &zout[cur + k * 64 + lane]);
        }
    }
}

extern "C" void kernel_launch(void* const* d_in, const int* in_sizes, int n_in,
                              void* d_out, int out_size, void* d_ws, size_t ws_size,
                              hipStream_t stream) {
    const float* x   = (const float*)d_in[0];   // [B,5]
    const float* W   = (const float*)d_in[1];   // [5,5]
    const float* bfc = (const float*)d_in[2];   // [5]
    float* out = (float*)d_out;                 // [B,5]

    int total_f4 = in_sizes[0] / 4;             // 5,242,880
    int f4_per_wave = F4_PER_TILE * TILES_PER_WAVE;                    // 1280
    int n_waves  = (total_f4 + f4_per_wave - 1) / f4_per_wave;         // 4096
    int grid     = (n_waves + WAVES_PER_BLOCK - 1) / WAVES_PER_BLOCK;  // 1024

    qpnet_kernel<<<grid, BLOCK, 0, stream>>>(x, W, bfc, out, total_f4);
}